// Round 1
// baseline (295.258 us; speedup 1.0000x reference)
//
#include <hip/hip_runtime.h>

#define D 64
#define KCODES 512
// N = 32*64*64 = 131072 rows, divisible by 256

// cc[k] = ||codebook_k||^2, recomputed every launch into d_ws (ws is re-poisoned)
__global__ void __launch_bounds__(256) vq_cc_kernel(const float* __restrict__ cb,
                                                    float* __restrict__ cc) {
    int k = blockIdx.x * 256 + threadIdx.x;
    if (k < KCODES) {
        float s = 0.f;
        #pragma unroll
        for (int d = 0; d < D; ++d) s = fmaf(cb[k * D + d], cb[k * D + d], s);
        cc[k] = s;
    }
}

// One thread per row. Row x lives in 64 VGPRs; codebook row addresses are
// wave-uniform -> scalar loads; hot loop is pure v_fma_f32 with SGPR operand.
__global__ void __launch_bounds__(256) vq_kernel(const float* __restrict__ x,
                                                 const float* __restrict__ cb,
                                                 const float* __restrict__ cc,
                                                 float* __restrict__ out) {
    const size_t row = (size_t)blockIdx.x * 256 + threadIdx.x;

    float xr[D];
    float xx = 0.f;
    #pragma unroll
    for (int d = 0; d < D; ++d) {
        xr[d] = x[row * D + d];
        xx = fmaf(xr[d], xr[d], xx);
    }

    float best = __builtin_inff();
    int bi = 0;
    for (int k = 0; k < KCODES; ++k) {
        // two accumulators, float2-shaped: lets the compiler form v_pk_fma_f32
        float dot0 = 0.f, dot1 = 0.f;
        #pragma unroll
        for (int d = 0; d < D; d += 2) {
            dot0 = fmaf(xr[d],     cb[k * D + d],     dot0);
            dot1 = fmaf(xr[d + 1], cb[k * D + d + 1], dot1);
        }
        // match reference expression order: (||x||^2 - 2*dot) + ||c||^2
        float dist = (xx - 2.f * (dot0 + dot1)) + cc[k];
        if (dist < best) { best = dist; bi = k; }  // strict < == first-occurrence argmin
    }

    const float* src = cb + (size_t)bi * D;
    #pragma unroll
    for (int d = 0; d < D; ++d) out[row * D + d] = src[d];
}

extern "C" void kernel_launch(void* const* d_in, const int* in_sizes, int n_in,
                              void* d_out, int out_size, void* d_ws, size_t ws_size,
                              hipStream_t stream) {
    const float* x  = (const float*)d_in[0];   // 131072 x 64
    const float* cb = (const float*)d_in[1];   // 512 x 64
    float* out = (float*)d_out;
    float* cc  = (float*)d_ws;                 // 512 floats

    vq_cc_kernel<<<2, 256, 0, stream>>>(cb, cc);

    const int N = in_sizes[0] / D;             // 131072
    vq_kernel<<<N / 256, 256, 0, stream>>>(x, cb, cc, out);
}